// Round 3
// baseline (356.590 us; speedup 1.0000x reference)
//
#include <hip/hip_runtime.h>
#include <hip/hip_bf16.h>

// GCN attention forward, MI355X. fp32 inputs (counter-proven R14).
// R20 FAILED (+4.5us): deeper gather pipelines neutral-negative (likely
// VGPR pressure at the 1024x4 cap). Reverted to R19 structure.
// R21 DIAGNOSTIC: every kernel launched TWICE (all idempotent). The dur
// delta vs the 276us baseline measures the true kernel total S:
//   dur ~= 276 + S + ~8us launch overhead.
// Model predicts S=50-60us (k1 adj-read floor ~21us dominating);
// inherited accounting claims S~130us. This round resolves which.
// k0 Wprep | k1 extract+fc(fp8) | k2 spmm(fp8)+qk | k3 attn(fp8)+v1+v2.

#define NN    4096
#define ROWS  8192
#define OFT   256
#define CAP   128
#define NBLK  512
#define RPB   16
#define EPSN  1e-12f
#define MFMA(a,b,c) __builtin_amdgcn_mfma_f32_16x16x32_bf16((a),(b),(c),0,0,0)

typedef unsigned short ushort_t;
typedef unsigned char  u8;
typedef __attribute__((ext_vector_type(8))) short bf16x8;
typedef __attribute__((ext_vector_type(4))) float f32x4;
typedef __attribute__((ext_vector_type(2))) float f32x2;

#define WP_FC   0
#define WP_Q    (16384 * 8)
#define WP_K    (WP_Q + 8192 * 8)
#define WP_V1   (WP_K + 8192 * 8)
#define WP_V2   (WP_V1 + 8192 * 8)

__device__ __forceinline__ float lo_f(unsigned u) { union { unsigned i; float f; } c; c.i = u << 16;          return c.f; }
__device__ __forceinline__ float hi_f(unsigned u) { union { unsigned i; float f; } c; c.i = u & 0xFFFF0000u;  return c.f; }
__device__ __forceinline__ float bf2f(ushort_t u) { union { unsigned i; float f; } c; c.i = (unsigned)u << 16; return c.f; }
__device__ __forceinline__ ushort_t f2bf(float f) {
    union { float f; unsigned i; } c; c.f = f;
    unsigned r = c.i + 0x7FFFu + ((c.i >> 16) & 1u);
    return (ushort_t)(r >> 16);
}
__device__ __forceinline__ unsigned pack2(float a, float b) {
    return (unsigned)f2bf(a) | ((unsigned)f2bf(b) << 16);
}

template<int CTRL>
__device__ __forceinline__ float dpp_add(float x) {
    union { float f; int i; } c; c.f = x;
    int y = __builtin_amdgcn_update_dpp(c.i, c.i, CTRL, 0xF, 0xF, false);
    union { int i; float f; } r; r.i = y;
    return x + r.f;
}

// ===================== k0: weight prep -> bf16 frag layout ==================
__global__ __launch_bounds__(256) void k0_prep(
    const float* __restrict__ Wfc, const float* __restrict__ Wq,
    const float* __restrict__ Wk,  const float* __restrict__ Wv1,
    const float* __restrict__ Wv2, ushort_t* __restrict__ Wp)
{
    int sid = blockIdx.x * 256 + threadIdx.x;
    const float* src; int K, local; ushort_t* dst;
    if (sid < 16384) { src = Wfc; K = 512; local = sid; dst = Wp + WP_FC + (size_t)local * 8; }
    else {
        int s = sid - 16384, which = s >> 13; local = s & 8191;
        const float* ws4[4] = {Wq, Wk, Wv1, Wv2};
        src = ws4[which]; K = 256;
        dst = Wp + WP_Q + (size_t)which * 65536 + (size_t)local * 8;
    }
    int col = local & 255, k8c = local >> 8;
    const float* p = src + (size_t)col * K + k8c * 8;
    float4 x0 = *(const float4*)p, x1 = *(const float4*)(p + 4);
    uint4 o; o.x = pack2(x0.x, x0.y); o.y = pack2(x0.z, x0.w);
    o.z = pack2(x1.x, x1.y); o.w = pack2(x1.z, x1.w);
    *(uint4*)dst = o;
}

// ============================ k1: extract + fc ==============================
__global__ __launch_bounds__(1024, 4) void k1_extract_fc(
    const float* __restrict__ seq, const float* __restrict__ adj,
    const ushort_t* __restrict__ Wp, u8* __restrict__ regA8,
    unsigned* __restrict__ gcols, int* __restrict__ cnt)
{
    __shared__ ushort_t Astage[64 * 17 * 8];
    __shared__ ushort_t csr_c[RPB * CAP];
    __shared__ int      csr_n[RPB];

    const int tid = threadIdx.x, wave = tid >> 6, lane = tid & 63;
    const int t16 = lane & 15, kq = lane >> 4;
    const int b = blockIdx.x, r0 = b * RPB;

    {   // extract: wave -> row; all 16 float4 loads up-front
        const float4* rowp = (const float4*)(adj + (size_t)(r0 + wave) * NN);
        float4 v[16];
#pragma unroll
        for (int t = 0; t < 16; ++t) v[t] = rowp[t * 64 + lane];
        int base = 0;
#pragma unroll
        for (int h = 0; h < 2; ++h) {
            int c = 0;
#pragma unroll
            for (int t = 0; t < 8; ++t) {
                const float4& x = v[h * 8 + t];
                c += (x.x > 0.f) + (x.y > 0.f) + (x.z > 0.f) + (x.w > 0.f);
            }
            int incl = c;
#pragma unroll
            for (int off = 1; off < 64; off <<= 1) {
                int y = __shfl_up(incl, off, 64);
                if (lane >= off) incl += y;
            }
            int p = base + incl - c;
            base += __shfl(incl, 63, 64);
#pragma unroll
            for (int t = 0; t < 8; ++t) {
                const float4& x = v[h * 8 + t];
                float f[4] = {x.x, x.y, x.z, x.w};
#pragma unroll
                for (int j = 0; j < 4; ++j)
                    if (f[j] > 0.f) {
                        if (p < CAP)
                            csr_c[wave * CAP + p] = (ushort_t)(((h * 8 + t) * 64 + lane) * 4 + j);
                        ++p;
                    }
            }
        }
        if (lane == 0) csr_n[wave] = (base < CAP) ? base : CAP;
    }
    __syncthreads();
    {
        const unsigned* cc = (const unsigned*)csr_c;
        if (tid < RPB * CAP / 2) gcols[b * (RPB * CAP / 2) + tid] = cc[tid];
        if (tid < RPB) cnt[r0 + tid] = csr_n[tid];
    }

    // ---- stage seq 16 x 512 (fp32 -> bf16, k-major frag layout)
    {
        int row = tid >> 6, seg = tid & 63;
        const float* p = seq + (size_t)(r0 + row) * 512 + seg * 8;
        float4 x0 = *(const float4*)p, x1 = *(const float4*)(p + 4);
        uint4 a;
        a.x = pack2(x0.x, x0.y); a.y = pack2(x0.z, x0.w);
        a.z = pack2(x1.x, x1.y); a.w = pack2(x1.z, x1.w);
        *(bf16x8*)(Astage + ((size_t)seg * 17 + row) * 8) = *(bf16x8*)&a;
    }
    __syncthreads();

    // ---- fc GEMM: wave -> 16 cols; epilogue -> fp8 x16 byte stores
    {
        const int col = wave * 16 + t16;
        const ushort_t* Wm = Wp + WP_FC;
        f32x4 a0 = {0.f, 0.f, 0.f, 0.f};
        for (int bch = 0; bch < 4; ++bch) {
            bf16x8 wb[4];
#pragma unroll
            for (int c2 = 0; c2 < 4; ++c2) {
                int k8c = (bch * 4 + c2) * 4 + kq;
                wb[c2] = *(const bf16x8*)(Wm + ((size_t)k8c * 256 + col) * 8);
            }
#pragma unroll
            for (int c2 = 0; c2 < 4; ++c2) {
                int c = bch * 4 + c2;
                bf16x8 af = *(const bf16x8*)(Astage + ((size_t)(c * 4 + kq) * 17 + t16) * 8);
                a0 = MFMA(af, wb[c2], a0);
            }
        }
#pragma unroll
        for (int r = 0; r < 4; ++r) {
            int t8 = __builtin_amdgcn_cvt_pk_fp8_f32(a0[r] * 16.f, 0.f, 0, false);
            regA8[(size_t)(r0 + kq * 4 + r) * OFT + col] = (u8)(t8 & 0xFF);
        }
    }
}

// ===================== k2: spmm + q/k GEMM + norm + loss ====================
// spmm: wave -> row; 4 edge groups x 16 lanes; lane loads ONE uint4 (16 fp8
// dims) per edge -> 16 requests/edge; 2-deep prefetch; cross-group
// reduce once per row. q/k GEMM: 16 waves (0-7 q, 8-15 k), 32 cols each.
__global__ __launch_bounds__(1024, 4) void k2_spmm_qk(
    const u8* __restrict__ regA8, unsigned* __restrict__ KO8,
    ushort_t* __restrict__ regQ, const ushort_t* __restrict__ Wp,
    const unsigned* __restrict__ gcols, const int* __restrict__ cnt,
    float* __restrict__ part)
{
    __shared__ ushort_t Astage[32 * 17 * 8];
    __shared__ ushort_t csr_c[RPB * CAP];
    __shared__ ushort_t qn_l[RPB * OFT];
    __shared__ float    red[2][RPB][8];
    __shared__ float    dlred[16];

    const int tid = threadIdx.x, wave = tid >> 6, lane = tid & 63;
    const int t16 = lane & 15, kq = lane >> 4, grp = lane >> 4;
    const int b = blockIdx.x, r0 = b * RPB;
    const size_t batb = (size_t)(b >> 8) * 4096;

    {
        unsigned* cc = (unsigned*)csr_c;
        if (tid < RPB * CAP / 2) cc[tid] = gcols[b * (RPB * CAP / 2) + tid];
    }
    __syncthreads();

    // ---- spmm: wave -> row r0+wave
    {
        const int rl = wave;
        const int n = cnt[r0 + rl];
        const u8* gA = regA8 + batb * OFT;
        float a16[16];
#pragma unroll
        for (int j = 0; j < 16; ++j) a16[j] = 0.f;
        const int nIter = (n + 3) >> 2;
        uint4 v;
        {
            int e0 = grp; int val0 = (e0 < n);
            int col0 = csr_c[rl * CAP + (val0 ? e0 : 0)];
            v = *(const uint4*)(gA + (size_t)col0 * OFT + t16 * 16);
        }
        for (int it = 0; it < nIter; ++it) {
            uint4 vn;
            if (it + 1 < nIter) {
                int e1 = (it + 1) * 4 + grp; int val1 = (e1 < n);
                int col1 = csr_c[rl * CAP + (val1 ? e1 : 0)];
                vn = *(const uint4*)(gA + (size_t)col1 * OFT + t16 * 16);
            }
            int e = it * 4 + grp;
            if (e < n) {
                unsigned w4[4] = {v.x, v.y, v.z, v.w};
#pragma unroll
                for (int i2 = 0; i2 < 4; ++i2) {
                    f32x2 x01 = __builtin_amdgcn_cvt_pk_f32_fp8((int)w4[i2], false);
                    f32x2 x23 = __builtin_amdgcn_cvt_pk_f32_fp8((int)w4[i2], true);
                    a16[4*i2+0] += x01.x; a16[4*i2+1] += x01.y;
                    a16[4*i2+2] += x23.x; a16[4*i2+3] += x23.y;
                }
            }
            v = vn;
        }
#pragma unroll
        for (int j = 0; j < 16; ++j) {
            a16[j] += __shfl_xor(a16[j], 16, 64);
            a16[j] += __shfl_xor(a16[j], 32, 64);
        }
        float iv = 1.f / (16.f * (float)max(n, 1));
        // lane (grp,t16) owns dims t16*16 + grp*4 .. +3 after reduction
        float o0 = a16[grp*4+0]*iv, o1 = a16[grp*4+1]*iv;
        float o2 = a16[grp*4+2]*iv, o3 = a16[grp*4+3]*iv;
        // KO8 outb half: chunk = t16*4+grp
        int uo = 0;
        uo = __builtin_amdgcn_cvt_pk_fp8_f32(o0*16.f, o1*16.f, uo, false);
        uo = __builtin_amdgcn_cvt_pk_fp8_f32(o2*16.f, o3*16.f, uo, true);
        KO8[(size_t)(r0 + rl) * 128 + (t16 * 4 + grp) * 2 + 1] = (unsigned)uo;
        // Astage frag tile (bf16): dims d0 = t16*16 + grp*4
        int d0 = t16 * 16 + grp * 4;
        int q8c = d0 >> 3, off = d0 & 7;
        uint2 st; st.x = pack2(o0, o1); st.y = pack2(o2, o3);
        *(uint2*)(Astage + ((size_t)q8c * 17 + rl) * 8 + off) = st;
    }
    __syncthreads();

    // ---- q/k GEMM: waves 0-7 q, 8-15 k; wave -> 32 cols
    const int isK = wave >> 3, w8 = wave & 7;
    const ushort_t* Wm = Wp + (isK ? WP_K : WP_Q);
    f32x4 acc[2];
    acc[0] = (f32x4){0.f,0.f,0.f,0.f};
    acc[1] = (f32x4){0.f,0.f,0.f,0.f};
    for (int bch = 0; bch < 2; ++bch) {
        bf16x8 wb[2][4];
#pragma unroll
        for (int j = 0; j < 2; ++j)
#pragma unroll
            for (int c2 = 0; c2 < 4; ++c2) {
                int col = w8 * 32 + j * 16 + t16;
                int k8c = (bch * 4 + c2) * 4 + kq;
                wb[j][c2] = *(const bf16x8*)(Wm + ((size_t)k8c * 256 + col) * 8);
            }
#pragma unroll
        for (int c2 = 0; c2 < 4; ++c2) {
            int c = bch * 4 + c2;
            bf16x8 af = *(const bf16x8*)(Astage + ((size_t)(c*4 + kq) * 17 + t16) * 8);
            acc[0] = MFMA(af, wb[0][c2], acc[0]);
            acc[1] = MFMA(af, wb[1][c2], acc[1]);
        }
    }
#pragma unroll
    for (int r = 0; r < 4; ++r) {
        float s = acc[0][r]*acc[0][r] + acc[1][r]*acc[1][r];
#pragma unroll
        for (int off = 1; off < 16; off <<= 1) s += __shfl_xor(s, off, 16);
        if (t16 == 0) red[isK][kq*4 + r][w8] = s;
    }
    __syncthreads();
#pragma unroll
    for (int r = 0; r < 4; ++r) {
        int row = kq * 4 + r;
        float s = 0.f;
#pragma unroll
        for (int j = 0; j < 8; ++j) s += red[isK][row][j];
        float inv = 1.f / fmaxf(sqrtf(s), EPSN);
#pragma unroll
        for (int j = 0; j < 2; ++j) {
            int col = w8 * 32 + j * 16 + t16;
            float v = acc[j][r] * inv;
            acc[j][r] = v;
            if (isK) {
                int t8 = __builtin_amdgcn_cvt_pk_fp8_f32(v * 16.f, 0.f, 0, false);
                ((u8*)KO8)[(size_t)(r0 + row) * 512 + (col >> 2) * 8 + (col & 3)] =
                    (u8)(t8 & 0xFF);
            } else {
                ushort_t uv = f2bf(v);
                qn_l[row * OFT + col] = uv;
                regQ[(size_t)(r0 + row) * OFT + col] = uv;
            }
        }
    }
    __syncthreads();
    if (isK) {
        float dl = 0.f;
#pragma unroll
        for (int r = 0; r < 4; ++r) {
            int row = kq * 4 + r;
#pragma unroll
            for (int j = 0; j < 2; ++j) {
                int col = w8 * 32 + j * 16 + t16;
                float d = bf2f(qn_l[row * OFT + col]) - acc[j][r];
                dl += d * d;
            }
        }
#pragma unroll
        for (int off = 1; off < 64; off <<= 1) dl += __shfl_xor(dl, off, 64);
        if (lane == 0) dlred[wave] = dl;
    }
    __syncthreads();
    if (tid == 0) {
        float s = 0.f;
#pragma unroll
        for (int j = 8; j < 16; ++j) s += dlred[j];
        part[b] = s;
    }
}

// ============== k3: fused attention + v1 + v2 (16 waves, 16 rows) ===========
__global__ __launch_bounds__(1024, 4) void k3_fused(
    const unsigned* __restrict__ KO8, const ushort_t* __restrict__ regQ,
    const unsigned* __restrict__ gcols, const int* __restrict__ cnt,
    const ushort_t* __restrict__ Wp, const float* __restrict__ a_v,
    const float* __restrict__ a_act, const float* __restrict__ biasv,
    const float* __restrict__ part, float* __restrict__ out)
{
    __shared__ ushort_t csr_c[RPB * CAP];
    __shared__ ushort_t Astage[32 * 17 * 8];   // ctx frag layout
    __shared__ ushort_t Hl[32 * 17 * 8];       // h frag layout
    __shared__ float    s8[16];

    const int tid = threadIdx.x, wave = tid >> 6, lane = tid & 63;
    const int t16 = lane & 15, kq = lane >> 4, grp = lane >> 4;
    const int b = blockIdx.x, r0 = b * RPB;
    const size_t batb = (size_t)(b >> 8) * 4096;

    if (b == 0 && tid < 512) {     // div_loss finalize
        float s = part[tid];
#pragma unroll
        for (int off = 32; off; off >>= 1) s += __shfl_down(s, off, 64);
        if (lane == 0) s8[wave] = s;
    }
    __syncthreads();
    if (b == 0 && tid == 0) {
        float t = 0.f;
#pragma unroll
        for (int j = 0; j < 8; ++j) t += s8[j];
        out[(size_t)ROWS * OFT] = t * (1.f / 8192.f);
    }

    {
        unsigned* cc = (unsigned*)csr_c;
        if (tid < RPB * CAP / 2) cc[tid] = gcols[b * (RPB * CAP / 2) + tid];
    }
    __syncthreads();

    // ---- attention: wave -> row; 4 edge slots; 2-deep prefetch; fp8 KO
    {
        const int row = r0 + wave;
        const int n = cnt[row];
        float q[16];
        {
            const ushort_t* qp = regQ + (size_t)row * OFT + t16 * 16;
            uint4 a = *(const uint4*)qp, bq = *(const uint4*)(qp + 8);
            unsigned uu[8] = {a.x, a.y, a.z, a.w, bq.x, bq.y, bq.z, bq.w};
#pragma unroll
            for (int j = 0; j < 8; ++j) { q[2*j] = lo_f(uu[j]); q[2*j+1] = hi_f(uu[j]); }
        }
        const unsigned* gKO = KO8 + batb * 128;
        float c[16];
#pragma unroll
        for (int j = 0; j < 16; ++j) c[j] = 0.f;
        float sE = 0.f;
        const int nIter = (n + 3) >> 2;
        uint4 v0, v1;
        {
            int e0 = grp; int val0 = (e0 < n);
            int col0 = csr_c[wave * CAP + (val0 ? e0 : 0)];
            const uint4* p0 = (const uint4*)(gKO + (size_t)col0 * 128 + t16 * 8);
            v0 = p0[0]; v1 = p0[1];
        }
        for (int it = 0; it < nIter; ++it) {
            uint4 n0, n1;
            if (it + 1 < nIter) {
                int e1 = (it + 1) * 4 + grp; int val1 = (e1 < n);
                int col1 = csr_c[wave * CAP + (val1 ? e1 : 0)];
                const uint4* p1 = (const uint4*)(gKO + (size_t)col1 * 128 + t16 * 8);
                n0 = p1[0]; n1 = p1[1];
            }
            int e = it * 4 + grp;
            int valid = (e < n);
            float d = 0.f;
            unsigned kw[4] = {v0.x, v0.z, v1.x, v1.z};
#pragma unroll
            for (int i2 = 0; i2 < 4; ++i2) {
                f32x2 k01 = __builtin_amdgcn_cvt_pk_f32_fp8((int)kw[i2], false);
                f32x2 k23 = __builtin_amdgcn_cvt_pk_f32_fp8((int)kw[i2], true);
                d += q[4*i2+0]*k01.x + q[4*i2+1]*k01.y + q[4*i2+2]*k23.x + q[4*i2+3]*k23.y;
            }
            d = dpp_add<0xB1>(d);    // quad xor1
            d = dpp_add<0x4E>(d);    // quad xor2
            d = dpp_add<0x124>(d);   // row_ror:4
            d = dpp_add<0x128>(d);   // row_ror:8
            float es = __expf(d * 0.0625f);   // unscale kn x16; |score|<=1
            es = valid ? es : 0.f;
            sE += es;
            unsigned ow[4] = {v0.y, v0.w, v1.y, v1.w};
#pragma unroll
            for (int i2 = 0; i2 < 4; ++i2) {
                f32x2 o01 = __builtin_amdgcn_cvt_pk_f32_fp8((int)ow[i2], false);
                f32x2 o23 = __builtin_amdgcn_cvt_pk_f32_fp8((int)ow[i2], true);
                c[4*i2+0] += es * o01.x; c[4*i2+1] += es * o01.y;
                c[4*i2+2] += es * o23.x; c[4*i2+3] += es * o23.y;
            }
            v0 = n0; v1 = n1;
        }
#pragma unroll
        for (int j = 0; j < 16; ++j) {
            c[j] += __shfl_xor(c[j], 16, 64);
            c[j] += __shfl_xor(c[j], 32, 64);
        }
        sE += __shfl_xor(sE, 16, 64);
        sE += __shfl_xor(sE, 32, 64);
        float inv16 = 0.0625f / sE;          // unscale outb x16 + softmax norm
        {
            int d0 = t16 * 16 + grp * 4;
            int q8c = d0 >> 3, off = d0 & 7;
            uint2 st; st.x = pack2(c[grp*4]*inv16, c[grp*4+1]*inv16);
            st.y = pack2(c[grp*4+2]*inv16, c[grp*4+3]*inv16);
            *(uint2*)(Astage + ((size_t)q8c * 17 + wave) * 8 + off) = st;
        }
    }
    __syncthreads();

    // ---- v1 GEMM + PReLU(a_v) -> Hl
    const int col = wave * 16 + t16;
    {
        const ushort_t* Wm = Wp + WP_V1;
        f32x4 h0 = {0.f,0.f,0.f,0.f};
        for (int bch = 0; bch < 2; ++bch) {
            bf16x8 wb[4];
#pragma unroll
            for (int c2 = 0; c2 < 4; ++c2) {
                int k8c = (bch * 4 + c2) * 4 + kq;
                wb[c2] = *(const bf16x8*)(Wm + ((size_t)k8c * 256 + col) * 8);
            }
#pragma unroll
            for (int c2 = 0; c2 < 4; ++c2) {
                int c = bch * 4 + c2;
                bf16x8 af = *(const bf16x8*)(Astage + ((size_t)(c*4 + kq) * 17 + t16) * 8);
                h0 = MFMA(af, wb[c2], h0);
            }
        }
        float av = *a_v;
        int q8c = col >> 3, off = col & 7;
#pragma unroll
        for (int r = 0; r < 4; ++r) {
            int row = kq * 4 + r;
            float x = h0[r]; x = (x >= 0.f) ? x : av * x;
            Hl[((size_t)q8c * 17 + row) * 8 + off] = f2bf(x);
        }
    }
    __syncthreads();

    // ---- v2 GEMM + bias + PReLU(a_act) -> out (fp32)
    {
        const ushort_t* Wm = Wp + WP_V2;
        f32x4 y0 = {0.f,0.f,0.f,0.f};
        for (int bch = 0; bch < 2; ++bch) {
            bf16x8 wb[4];
#pragma unroll
            for (int c2 = 0; c2 < 4; ++c2) {
                int k8c = (bch * 4 + c2) * 4 + kq;
                wb[c2] = *(const bf16x8*)(Wm + ((size_t)k8c * 256 + col) * 8);
            }
#pragma unroll
            for (int c2 = 0; c2 < 4; ++c2) {
                int c = bch * 4 + c2;
                bf16x8 af = *(const bf16x8*)(Hl + ((size_t)(c*4 + kq) * 17 + t16) * 8);
                y0 = MFMA(af, wb[c2], y0);
            }
        }
        float aa = *a_act;
        float bv = biasv[col];
#pragma unroll
        for (int r = 0; r < 4; ++r) {
            size_t row = (size_t)(r0 + kq * 4 + r);
            float x = y0[r] + bv; x = (x >= 0.f) ? x : aa * x;
            out[row * OFT + col] = x;
        }
    }
}

// ------------------------------------------------------------------- launch
extern "C" void kernel_launch(void* const* d_in, const int* in_sizes, int n_in,
                              void* d_out, int out_size, void* d_ws, size_t ws_size,
                              hipStream_t stream)
{
    const float* seq   = (const float*)d_in[0];
    const float* adj   = (const float*)d_in[1];
    const float* W_fc  = (const float*)d_in[2];
    const float* W_q   = (const float*)d_in[3];
    const float* W_k   = (const float*)d_in[4];
    const float* W_v1  = (const float*)d_in[5];
    const float* W_v2  = (const float*)d_in[6];
    const float* a_v   = (const float*)d_in[7];
    const float* a_act = (const float*)d_in[8];
    const float* bias  = (const float*)d_in[9];

    char* w = (char*)d_ws;
    u8*       regA8 = (u8*)w;                                // seq_fts fp8 2MB
    unsigned* KO8   = (unsigned*)(w + (4u  << 20));          // fp8 kn|outb 4MB
    ushort_t* regQ  = (ushort_t*)(w + (12u << 20));          // qn 4MB
    unsigned* gcols = (unsigned*)(w + (16u << 20));          // CSR u16 cols 2MB
    int*      cnt   = (int*)(w + (20u << 20));               // 32KB
    float*    part  = (float*)(w + (20u << 20) + 32768);     // 2KB
    ushort_t* Wp    = (ushort_t*)(w + (21u << 20));          // 768KB frag weights

    // R21 DIAGNOSTIC: every kernel launched twice (all idempotent).
    // dur - 276 - ~8us = true kernel total S.
    k0_prep<<<192, 256, 0, stream>>>(W_fc, W_q, W_k, W_v1, W_v2, Wp);
    k0_prep<<<192, 256, 0, stream>>>(W_fc, W_q, W_k, W_v1, W_v2, Wp);
    k1_extract_fc<<<NBLK, 1024, 0, stream>>>(seq, adj, Wp, regA8, gcols, cnt);
    k1_extract_fc<<<NBLK, 1024, 0, stream>>>(seq, adj, Wp, regA8, gcols, cnt);
    k2_spmm_qk<<<NBLK, 1024, 0, stream>>>(regA8, KO8, regQ, Wp, gcols, cnt, part);
    k2_spmm_qk<<<NBLK, 1024, 0, stream>>>(regA8, KO8, regQ, Wp, gcols, cnt, part);
    k3_fused<<<NBLK, 1024, 0, stream>>>(KO8, regQ, gcols, cnt, Wp,
                                        a_v, a_act, bias, part, (float*)d_out);
    k3_fused<<<NBLK, 1024, 0, stream>>>(KO8, regQ, gcols, cnt, Wp,
                                        a_v, a_act, bias, part, (float*)d_out);
}

// Round 4
// 274.723 us; speedup vs baseline: 1.2980x; 1.2980x over previous
//
#include <hip/hip_runtime.h>
#include <hip/hip_bf16.h>

// GCN attention forward, MI355X. fp32 inputs (counter-proven R14).
// R21 diagnostic: true kernel total S ~= 76us (window = ~200us harness
// fills + ~76us kernels). k1 ~22us (adj HBM floor). k2+k3 ~= 50us,
// TA-address-rate bound (~1 lane-addr/cyc/CU): k3 was 32 addrs/edge.
// R22: eliminate kn gather algebraically. score = (h[m]. out[n])*invnk[n]
// with h[m] = qn[m].Wk (computed in k2 from qn_l vs transposed-Wk frags),
// invnk from k2's k-norm reduce. k3 per-edge gather: ONE uint4/lane
// (out[n] 256B serves BOTH score dot and ctx sum) -> TA addrs halved.
// KO8 shrinks to 256B/row. regQ replaced by regH (= h, bf16).
// k0 Wprep(+WkT) | k1 extract+fc(fp8) | k2 spmm+qk+h | k3 attn+v1+v2.

#define NN    4096
#define ROWS  8192
#define OFT   256
#define CAP   128
#define NBLK  512
#define RPB   16
#define QLS   264   // qn_l row stride (ushort) — bank-spread for h-GEMM reads
#define EPSN  1e-12f
#define MFMA(a,b,c) __builtin_amdgcn_mfma_f32_16x16x32_bf16((a),(b),(c),0,0,0)

typedef unsigned short ushort_t;
typedef unsigned char  u8;
typedef __attribute__((ext_vector_type(8))) short bf16x8;
typedef __attribute__((ext_vector_type(4))) float f32x4;
typedef __attribute__((ext_vector_type(2))) float f32x2;

#define WP_FC   0
#define WP_Q    (16384 * 8)
#define WP_K    (WP_Q + 8192 * 8)
#define WP_V1   (WP_K + 8192 * 8)
#define WP_V2   (WP_V1 + 8192 * 8)
#define WP_KT   (WP_V2 + 8192 * 8)   // Wk transposed frags: [p-kmajor][o-col]

__device__ __forceinline__ float lo_f(unsigned u) { union { unsigned i; float f; } c; c.i = u << 16;          return c.f; }
__device__ __forceinline__ float hi_f(unsigned u) { union { unsigned i; float f; } c; c.i = u & 0xFFFF0000u;  return c.f; }
__device__ __forceinline__ float bf2f(ushort_t u) { union { unsigned i; float f; } c; c.i = (unsigned)u << 16; return c.f; }
__device__ __forceinline__ ushort_t f2bf(float f) {
    union { float f; unsigned i; } c; c.f = f;
    unsigned r = c.i + 0x7FFFu + ((c.i >> 16) & 1u);
    return (ushort_t)(r >> 16);
}
__device__ __forceinline__ unsigned pack2(float a, float b) {
    return (unsigned)f2bf(a) | ((unsigned)f2bf(b) << 16);
}

template<int CTRL>
__device__ __forceinline__ float dpp_add(float x) {
    union { float f; int i; } c; c.f = x;
    int y = __builtin_amdgcn_update_dpp(c.i, c.i, CTRL, 0xF, 0xF, false);
    union { int i; float f; } r; r.i = y;
    return x + r.f;
}

// ===================== k0: weight prep -> bf16 frag layout ==================
// sid<16384: Wfc. 16384..49151: Wq/Wk/Wv1/Wv2. 49152..57343: Wk^T frags
// (strided column reads) for k2's h-GEMM (h = qn . Wk, k-index = p).
__global__ __launch_bounds__(256) void k0_prep(
    const float* __restrict__ Wfc, const float* __restrict__ Wq,
    const float* __restrict__ Wk,  const float* __restrict__ Wv1,
    const float* __restrict__ Wv2, ushort_t* __restrict__ Wp)
{
    int sid = blockIdx.x * 256 + threadIdx.x;
    if (sid >= 49152) {            // WkT: frag (p8, col=o): Wk[p8*8+i][o]
        int t = sid - 49152;       // 0..8191
        int o = t & 255, p8 = t >> 8;
        ushort_t tmp[8];
#pragma unroll
        for (int i = 0; i < 8; ++i)
            tmp[i] = f2bf(Wk[(size_t)(p8 * 8 + i) * 256 + o]);
        *(bf16x8*)(Wp + WP_KT + (size_t)t * 8) = *(bf16x8*)tmp;
        return;
    }
    const float* src; int K, local; ushort_t* dst;
    if (sid < 16384) { src = Wfc; K = 512; local = sid; dst = Wp + WP_FC + (size_t)local * 8; }
    else {
        int s = sid - 16384, which = s >> 13; local = s & 8191;
        const float* ws4[4] = {Wq, Wk, Wv1, Wv2};
        src = ws4[which]; K = 256;
        dst = Wp + WP_Q + (size_t)which * 65536 + (size_t)local * 8;
    }
    int col = local & 255, k8c = local >> 8;
    const float* p = src + (size_t)col * K + k8c * 8;
    float4 x0 = *(const float4*)p, x1 = *(const float4*)(p + 4);
    uint4 o; o.x = pack2(x0.x, x0.y); o.y = pack2(x0.z, x0.w);
    o.z = pack2(x1.x, x1.y); o.w = pack2(x1.z, x1.w);
    *(uint4*)dst = o;
}

// ============================ k1: extract + fc ==============================
__global__ __launch_bounds__(1024, 4) void k1_extract_fc(
    const float* __restrict__ seq, const float* __restrict__ adj,
    const ushort_t* __restrict__ Wp, u8* __restrict__ regA8,
    unsigned* __restrict__ gcols, int* __restrict__ cnt)
{
    __shared__ ushort_t Astage[64 * 17 * 8];
    __shared__ ushort_t csr_c[RPB * CAP];
    __shared__ int      csr_n[RPB];

    const int tid = threadIdx.x, wave = tid >> 6, lane = tid & 63;
    const int t16 = lane & 15, kq = lane >> 4;
    const int b = blockIdx.x, r0 = b * RPB;

    {   // extract: wave -> row; all 16 float4 loads up-front
        const float4* rowp = (const float4*)(adj + (size_t)(r0 + wave) * NN);
        float4 v[16];
#pragma unroll
        for (int t = 0; t < 16; ++t) v[t] = rowp[t * 64 + lane];
        int base = 0;
#pragma unroll
        for (int h = 0; h < 2; ++h) {
            int c = 0;
#pragma unroll
            for (int t = 0; t < 8; ++t) {
                const float4& x = v[h * 8 + t];
                c += (x.x > 0.f) + (x.y > 0.f) + (x.z > 0.f) + (x.w > 0.f);
            }
            int incl = c;
#pragma unroll
            for (int off = 1; off < 64; off <<= 1) {
                int y = __shfl_up(incl, off, 64);
                if (lane >= off) incl += y;
            }
            int p = base + incl - c;
            base += __shfl(incl, 63, 64);
#pragma unroll
            for (int t = 0; t < 8; ++t) {
                const float4& x = v[h * 8 + t];
                float f[4] = {x.x, x.y, x.z, x.w};
#pragma unroll
                for (int j = 0; j < 4; ++j)
                    if (f[j] > 0.f) {
                        if (p < CAP)
                            csr_c[wave * CAP + p] = (ushort_t)(((h * 8 + t) * 64 + lane) * 4 + j);
                        ++p;
                    }
            }
        }
        if (lane == 0) csr_n[wave] = (base < CAP) ? base : CAP;
    }
    __syncthreads();
    {
        const unsigned* cc = (const unsigned*)csr_c;
        if (tid < RPB * CAP / 2) gcols[b * (RPB * CAP / 2) + tid] = cc[tid];
        if (tid < RPB) cnt[r0 + tid] = csr_n[tid];
    }

    // ---- stage seq 16 x 512 (fp32 -> bf16, k-major frag layout)
    {
        int row = tid >> 6, seg = tid & 63;
        const float* p = seq + (size_t)(r0 + row) * 512 + seg * 8;
        float4 x0 = *(const float4*)p, x1 = *(const float4*)(p + 4);
        uint4 a;
        a.x = pack2(x0.x, x0.y); a.y = pack2(x0.z, x0.w);
        a.z = pack2(x1.x, x1.y); a.w = pack2(x1.z, x1.w);
        *(bf16x8*)(Astage + ((size_t)seg * 17 + row) * 8) = *(bf16x8*)&a;
    }
    __syncthreads();

    // ---- fc GEMM: wave -> 16 cols; epilogue -> fp8 x16 byte stores
    {
        const int col = wave * 16 + t16;
        const ushort_t* Wm = Wp + WP_FC;
        f32x4 a0 = {0.f, 0.f, 0.f, 0.f};
        for (int bch = 0; bch < 4; ++bch) {
            bf16x8 wb[4];
#pragma unroll
            for (int c2 = 0; c2 < 4; ++c2) {
                int k8c = (bch * 4 + c2) * 4 + kq;
                wb[c2] = *(const bf16x8*)(Wm + ((size_t)k8c * 256 + col) * 8);
            }
#pragma unroll
            for (int c2 = 0; c2 < 4; ++c2) {
                int c = bch * 4 + c2;
                bf16x8 af = *(const bf16x8*)(Astage + ((size_t)(c * 4 + kq) * 17 + t16) * 8);
                a0 = MFMA(af, wb[c2], a0);
            }
        }
#pragma unroll
        for (int r = 0; r < 4; ++r) {
            int t8 = __builtin_amdgcn_cvt_pk_fp8_f32(a0[r] * 16.f, 0.f, 0, false);
            regA8[(size_t)(r0 + kq * 4 + r) * OFT + col] = (u8)(t8 & 0xFF);
        }
    }
}

// ============== k2: spmm + q/k GEMM + norm + loss + h-GEMM ==================
// spmm: wave -> row; 16-lane-per-edge uint4 loads, 2-deep prefetch.
// q/k GEMM: waves 0-7 q, 8-15 k. Then: invnk[row] stored (k-norm),
// h = qn . Wk via WP_KT frags (all 16 waves, 16 cols each) -> regH bf16.
__global__ __launch_bounds__(1024, 4) void k2_spmm_qk(
    const u8* __restrict__ regA8, unsigned* __restrict__ KO8,
    ushort_t* __restrict__ regH, const ushort_t* __restrict__ Wp,
    const unsigned* __restrict__ gcols, const int* __restrict__ cnt,
    float* __restrict__ part, float* __restrict__ invnk_g)
{
    __shared__ ushort_t Astage[32 * 17 * 8];
    __shared__ ushort_t csr_c[RPB * CAP];
    __shared__ ushort_t qn_l[RPB * QLS];
    __shared__ float    red[2][RPB][8];
    __shared__ float    dlred[16];

    const int tid = threadIdx.x, wave = tid >> 6, lane = tid & 63;
    const int t16 = lane & 15, kq = lane >> 4, grp = lane >> 4;
    const int b = blockIdx.x, r0 = b * RPB;
    const size_t batb = (size_t)(b >> 8) * 4096;

    {
        unsigned* cc = (unsigned*)csr_c;
        if (tid < RPB * CAP / 2) cc[tid] = gcols[b * (RPB * CAP / 2) + tid];
    }
    __syncthreads();

    // ---- spmm: wave -> row r0+wave
    {
        const int rl = wave;
        const int n = cnt[r0 + rl];
        const u8* gA = regA8 + batb * OFT;
        float a16[16];
#pragma unroll
        for (int j = 0; j < 16; ++j) a16[j] = 0.f;
        const int nIter = (n + 3) >> 2;
        uint4 v;
        {
            int e0 = grp; int val0 = (e0 < n);
            int col0 = csr_c[rl * CAP + (val0 ? e0 : 0)];
            v = *(const uint4*)(gA + (size_t)col0 * OFT + t16 * 16);
        }
        for (int it = 0; it < nIter; ++it) {
            uint4 vn;
            if (it + 1 < nIter) {
                int e1 = (it + 1) * 4 + grp; int val1 = (e1 < n);
                int col1 = csr_c[rl * CAP + (val1 ? e1 : 0)];
                vn = *(const uint4*)(gA + (size_t)col1 * OFT + t16 * 16);
            }
            int e = it * 4 + grp;
            if (e < n) {
                unsigned w4[4] = {v.x, v.y, v.z, v.w};
#pragma unroll
                for (int i2 = 0; i2 < 4; ++i2) {
                    f32x2 x01 = __builtin_amdgcn_cvt_pk_f32_fp8((int)w4[i2], false);
                    f32x2 x23 = __builtin_amdgcn_cvt_pk_f32_fp8((int)w4[i2], true);
                    a16[4*i2+0] += x01.x; a16[4*i2+1] += x01.y;
                    a16[4*i2+2] += x23.x; a16[4*i2+3] += x23.y;
                }
            }
            v = vn;
        }
#pragma unroll
        for (int j = 0; j < 16; ++j) {
            a16[j] += __shfl_xor(a16[j], 16, 64);
            a16[j] += __shfl_xor(a16[j], 32, 64);
        }
        float iv = 1.f / (16.f * (float)max(n, 1));
        // lane (grp,t16) owns dims t16*16 + grp*4 .. +3 after reduction
        float o0 = a16[grp*4+0]*iv, o1 = a16[grp*4+1]*iv;
        float o2 = a16[grp*4+2]*iv, o3 = a16[grp*4+3]*iv;
        // KO8 (outb only now, 256B/row): chunk = t16*4+grp
        int uo = 0;
        uo = __builtin_amdgcn_cvt_pk_fp8_f32(o0*16.f, o1*16.f, uo, false);
        uo = __builtin_amdgcn_cvt_pk_fp8_f32(o2*16.f, o3*16.f, uo, true);
        KO8[(size_t)(r0 + rl) * 64 + (t16 * 4 + grp)] = (unsigned)uo;
        // Astage frag tile (bf16): dims d0 = t16*16 + grp*4
        int d0 = t16 * 16 + grp * 4;
        int q8c = d0 >> 3, off = d0 & 7;
        uint2 st; st.x = pack2(o0, o1); st.y = pack2(o2, o3);
        *(uint2*)(Astage + ((size_t)q8c * 17 + rl) * 8 + off) = st;
    }
    __syncthreads();

    // ---- q/k GEMM: waves 0-7 q, 8-15 k; wave -> 32 cols
    const int isK = wave >> 3, w8 = wave & 7;
    const ushort_t* Wm = Wp + (isK ? WP_K : WP_Q);
    f32x4 acc[2];
    acc[0] = (f32x4){0.f,0.f,0.f,0.f};
    acc[1] = (f32x4){0.f,0.f,0.f,0.f};
    for (int bch = 0; bch < 2; ++bch) {
        bf16x8 wb[2][4];
#pragma unroll
        for (int j = 0; j < 2; ++j)
#pragma unroll
            for (int c2 = 0; c2 < 4; ++c2) {
                int col = w8 * 32 + j * 16 + t16;
                int k8c = (bch * 4 + c2) * 4 + kq;
                wb[j][c2] = *(const bf16x8*)(Wm + ((size_t)k8c * 256 + col) * 8);
            }
#pragma unroll
        for (int c2 = 0; c2 < 4; ++c2) {
            int c = bch * 4 + c2;
            bf16x8 af = *(const bf16x8*)(Astage + ((size_t)(c*4 + kq) * 17 + t16) * 8);
            acc[0] = MFMA(af, wb[0][c2], acc[0]);
            acc[1] = MFMA(af, wb[1][c2], acc[1]);
        }
    }
#pragma unroll
    for (int r = 0; r < 4; ++r) {
        float s = acc[0][r]*acc[0][r] + acc[1][r]*acc[1][r];
#pragma unroll
        for (int off = 1; off < 16; off <<= 1) s += __shfl_xor(s, off, 16);
        if (t16 == 0) red[isK][kq*4 + r][w8] = s;
    }
    __syncthreads();
#pragma unroll
    for (int r = 0; r < 4; ++r) {
        int row = kq * 4 + r;
        float s = 0.f;
#pragma unroll
        for (int j = 0; j < 8; ++j) s += red[isK][row][j];
        float inv = 1.f / fmaxf(sqrtf(s), EPSN);
        if (isK && w8 == 0 && t16 == 0) invnk_g[r0 + row] = inv;
#pragma unroll
        for (int j = 0; j < 2; ++j) {
            int col = w8 * 32 + j * 16 + t16;
            float v = acc[j][r] * inv;
            acc[j][r] = v;
            if (!isK) qn_l[row * QLS + col] = f2bf(v);
        }
    }
    __syncthreads();
    if (isK) {
        float dl = 0.f;
#pragma unroll
        for (int r = 0; r < 4; ++r) {
            int row = kq * 4 + r;
#pragma unroll
            for (int j = 0; j < 2; ++j) {
                int col = w8 * 32 + j * 16 + t16;
                float d = bf2f(qn_l[row * QLS + col]) - acc[j][r];
                dl += d * d;
            }
        }
#pragma unroll
        for (int off = 1; off < 64; off <<= 1) dl += __shfl_xor(dl, off, 64);
        if (lane == 0) dlred[wave] = dl;
    }
    __syncthreads();

    // ---- h-GEMM: h[m] = qn[m] . Wk (k-index = p) via WP_KT; 16 waves x 16 cols
    {
        const ushort_t* WmT = Wp + WP_KT;
        const int colh = wave * 16 + t16;
        f32x4 h0 = {0.f, 0.f, 0.f, 0.f};
        for (int bch = 0; bch < 2; ++bch) {
            bf16x8 wb[4];
#pragma unroll
            for (int c2 = 0; c2 < 4; ++c2) {
                int k8c = (bch * 4 + c2) * 4 + kq;
                wb[c2] = *(const bf16x8*)(WmT + ((size_t)k8c * 256 + colh) * 8);
            }
#pragma unroll
            for (int c2 = 0; c2 < 4; ++c2) {
                int k8c = (bch * 4 + c2) * 4 + kq;
                bf16x8 af = *(const bf16x8*)(qn_l + (size_t)t16 * QLS + k8c * 8);
                h0 = MFMA(af, wb[c2], h0);
            }
        }
#pragma unroll
        for (int r = 0; r < 4; ++r) {
            int row = kq * 4 + r;
            regH[(size_t)(r0 + row) * OFT + colh] = f2bf(h0[r]);
        }
    }
    if (tid == 0) {
        float s = 0.f;
#pragma unroll
        for (int j = 8; j < 16; ++j) s += dlred[j];
        part[b] = s;
    }
}

// ============== k3: fused attention + v1 + v2 (16 waves, 16 rows) ===========
// Per edge: ONE uint4/lane (out[n] fp8 256B) serves BOTH score dot
// (vs h[m], bf16) and ctx accumulation. invnk staged per-row in LDS.
__global__ __launch_bounds__(1024, 4) void k3_fused(
    const unsigned* __restrict__ KO8, const ushort_t* __restrict__ regH,
    const unsigned* __restrict__ gcols, const int* __restrict__ cnt,
    const ushort_t* __restrict__ Wp, const float* __restrict__ a_v,
    const float* __restrict__ a_act, const float* __restrict__ biasv,
    const float* __restrict__ part, const float* __restrict__ invnk_g,
    float* __restrict__ out)
{
    __shared__ ushort_t csr_c[RPB * CAP];
    __shared__ float    invl[RPB][CAP];
    __shared__ ushort_t Astage[32 * 17 * 8];   // ctx frag layout
    __shared__ ushort_t Hl[32 * 17 * 8];       // h frag layout
    __shared__ float    s8[16];

    const int tid = threadIdx.x, wave = tid >> 6, lane = tid & 63;
    const int t16 = lane & 15, kq = lane >> 4, grp = lane >> 4;
    const int b = blockIdx.x, r0 = b * RPB;
    const size_t batb = (size_t)(b >> 8) * 4096;

    if (b == 0 && tid < 512) {     // div_loss finalize
        float s = part[tid];
#pragma unroll
        for (int off = 32; off; off >>= 1) s += __shfl_down(s, off, 64);
        if (lane == 0) s8[wave] = s;
    }
    __syncthreads();
    if (b == 0 && tid == 0) {
        float t = 0.f;
#pragma unroll
        for (int j = 0; j < 8; ++j) t += s8[j];
        out[(size_t)ROWS * OFT] = t * (1.f / 8192.f);
    }

    {
        unsigned* cc = (unsigned*)csr_c;
        if (tid < RPB * CAP / 2) cc[tid] = gcols[b * (RPB * CAP / 2) + tid];
    }
    __syncthreads();

    // ---- attention: wave -> row; 4 edge slots; 2-deep prefetch
    {
        const int row = r0 + wave;
        const int n = cnt[row];
        // stage invnk*0.0625 for this row's edges (wave-local LDS)
#pragma unroll
        for (int s = 0; s < 2; ++s) {
            int e = lane + s * 64;
            if (e < n) {
                int col = csr_c[wave * CAP + e];
                invl[wave][e] = invnk_g[batb + col] * 0.0625f;
            }
        }
        float q[16];
        {
            const ushort_t* qp = regH + (size_t)row * OFT + t16 * 16;
            uint4 a = *(const uint4*)qp, bq = *(const uint4*)(qp + 8);
            unsigned uu[8] = {a.x, a.y, a.z, a.w, bq.x, bq.y, bq.z, bq.w};
#pragma unroll
            for (int j = 0; j < 8; ++j) { q[2*j] = lo_f(uu[j]); q[2*j+1] = hi_f(uu[j]); }
        }
        const unsigned* gKO = KO8 + batb * 64;
        float c[16];
#pragma unroll
        for (int j = 0; j < 16; ++j) c[j] = 0.f;
        float sE = 0.f;
        const int nIter = (n + 3) >> 2;
        uint4 v;
        {
            int e0 = grp; int val0 = (e0 < n);
            int col0 = csr_c[wave * CAP + (val0 ? e0 : 0)];
            v = *(const uint4*)(gKO + (size_t)col0 * 64 + t16 * 4);
        }
        for (int it = 0; it < nIter; ++it) {
            uint4 vn;
            if (it + 1 < nIter) {
                int e1 = (it + 1) * 4 + grp; int val1 = (e1 < n);
                int col1 = csr_c[wave * CAP + (val1 ? e1 : 0)];
                vn = *(const uint4*)(gKO + (size_t)col1 * 64 + t16 * 4);
            }
            int e = it * 4 + grp;
            int valid = (e < n);
            // unpack out[n] slice once; reuse for dot and ctx
            float o[16];
            unsigned w4[4] = {v.x, v.y, v.z, v.w};
#pragma unroll
            for (int i2 = 0; i2 < 4; ++i2) {
                f32x2 x01 = __builtin_amdgcn_cvt_pk_f32_fp8((int)w4[i2], false);
                f32x2 x23 = __builtin_amdgcn_cvt_pk_f32_fp8((int)w4[i2], true);
                o[4*i2+0] = x01.x; o[4*i2+1] = x01.y;
                o[4*i2+2] = x23.x; o[4*i2+3] = x23.y;
            }
            float d = 0.f;
#pragma unroll
            for (int j = 0; j < 16; ++j) d += q[j] * o[j];
            d = dpp_add<0xB1>(d);    // quad xor1
            d = dpp_add<0x4E>(d);    // quad xor2
            d = dpp_add<0x124>(d);   // row_ror:4
            d = dpp_add<0x128>(d);   // row_ror:8
            float iv16v = invl[wave][valid ? e : 0];
            float es = __expf(d * iv16v);   // unscale outb x16 + k-norm
            es = valid ? es : 0.f;
            sE += es;
#pragma unroll
            for (int j = 0; j < 16; ++j) c[j] += es * o[j];
            v = vn;
        }
#pragma unroll
        for (int j = 0; j < 16; ++j) {
            c[j] += __shfl_xor(c[j], 16, 64);
            c[j] += __shfl_xor(c[j], 32, 64);
        }
        sE += __shfl_xor(sE, 16, 64);
        sE += __shfl_xor(sE, 32, 64);
        float inv16 = 0.0625f / sE;          // unscale outb x16 + softmax norm
        {
            int d0 = t16 * 16 + grp * 4;
            int q8c = d0 >> 3, off = d0 & 7;
            uint2 st; st.x = pack2(c[grp*4]*inv16, c[grp*4+1]*inv16);
            st.y = pack2(c[grp*4+2]*inv16, c[grp*4+3]*inv16);
            *(uint2*)(Astage + ((size_t)q8c * 17 + wave) * 8 + off) = st;
        }
    }
    __syncthreads();

    // ---- v1 GEMM + PReLU(a_v) -> Hl
    const int col = wave * 16 + t16;
    {
        const ushort_t* Wm = Wp + WP_V1;
        f32x4 h0 = {0.f,0.f,0.f,0.f};
        for (int bch = 0; bch < 2; ++bch) {
            bf16x8 wb[4];
#pragma unroll
            for (int c2 = 0; c2 < 4; ++c2) {
                int k8c = (bch * 4 + c2) * 4 + kq;
                wb[c2] = *(const bf16x8*)(Wm + ((size_t)k8c * 256 + col) * 8);
            }
#pragma unroll
            for (int c2 = 0; c2 < 4; ++c2) {
                int c = bch * 4 + c2;
                bf16x8 af = *(const bf16x8*)(Astage + ((size_t)(c*4 + kq) * 17 + t16) * 8);
                h0 = MFMA(af, wb[c2], h0);
            }
        }
        float av = *a_v;
        int q8c = col >> 3, off = col & 7;
#pragma unroll
        for (int r = 0; r < 4; ++r) {
            int row = kq * 4 + r;
            float x = h0[r]; x = (x >= 0.f) ? x : av * x;
            Hl[((size_t)q8c * 17 + row) * 8 + off] = f2bf(x);
        }
    }
    __syncthreads();

    // ---- v2 GEMM + bias + PReLU(a_act) -> out (fp32)
    {
        const ushort_t* Wm = Wp + WP_V2;
        f32x4 y0 = {0.f,0.f,0.f,0.f};
        for (int bch = 0; bch < 2; ++bch) {
            bf16x8 wb[4];
#pragma unroll
            for (int c2 = 0; c2 < 4; ++c2) {
                int k8c = (bch * 4 + c2) * 4 + kq;
                wb[c2] = *(const bf16x8*)(Wm + ((size_t)k8c * 256 + col) * 8);
            }
#pragma unroll
            for (int c2 = 0; c2 < 4; ++c2) {
                int c = bch * 4 + c2;
                bf16x8 af = *(const bf16x8*)(Hl + ((size_t)(c*4 + kq) * 17 + t16) * 8);
                y0 = MFMA(af, wb[c2], y0);
            }
        }
        float aa = *a_act;
        float bv = biasv[col];
#pragma unroll
        for (int r = 0; r < 4; ++r) {
            size_t row = (size_t)(r0 + kq * 4 + r);
            float x = y0[r] + bv; x = (x >= 0.f) ? x : aa * x;
            out[row * OFT + col] = x;
        }
    }
}

// ------------------------------------------------------------------- launch
extern "C" void kernel_launch(void* const* d_in, const int* in_sizes, int n_in,
                              void* d_out, int out_size, void* d_ws, size_t ws_size,
                              hipStream_t stream)
{
    const float* seq   = (const float*)d_in[0];
    const float* adj   = (const float*)d_in[1];
    const float* W_fc  = (const float*)d_in[2];
    const float* W_q   = (const float*)d_in[3];
    const float* W_k   = (const float*)d_in[4];
    const float* W_v1  = (const float*)d_in[5];
    const float* W_v2  = (const float*)d_in[6];
    const float* a_v   = (const float*)d_in[7];
    const float* a_act = (const float*)d_in[8];
    const float* bias  = (const float*)d_in[9];

    char* w = (char*)d_ws;
    u8*       regA8 = (u8*)w;                                // seq_fts fp8 2MB
    unsigned* KO8   = (unsigned*)(w + (4u  << 20));          // fp8 outb 2MB
    ushort_t* regH  = (ushort_t*)(w + (12u << 20));          // h=qn.Wk bf16 4MB
    unsigned* gcols = (unsigned*)(w + (16u << 20));          // CSR u16 cols 2MB
    int*      cnt   = (int*)(w + (20u << 20));               // 32KB
    float*    part  = (float*)(w + (20u << 20) + 32768);     // 2KB
    float*    invnk = (float*)(w + (20u << 20) + 65536);     // 32KB
    ushort_t* Wp    = (ushort_t*)(w + (21u << 20));          // 896KB frag weights

    k0_prep<<<224, 256, 0, stream>>>(W_fc, W_q, W_k, W_v1, W_v2, Wp);
    k1_extract_fc<<<NBLK, 1024, 0, stream>>>(seq, adj, Wp, regA8, gcols, cnt);
    k2_spmm_qk<<<NBLK, 1024, 0, stream>>>(regA8, KO8, regH, Wp, gcols, cnt,
                                          part, invnk);
    k3_fused<<<NBLK, 1024, 0, stream>>>(KO8, regH, gcols, cnt, Wp,
                                        a_v, a_act, bias, part, invnk,
                                        (float*)d_out);
}